// Round 3
// baseline (413.649 us; speedup 1.0000x reference)
//
#include <hip/hip_runtime.h>

typedef unsigned short ushort_t;
typedef _Float16 half8 __attribute__((ext_vector_type(8)));
typedef short short8 __attribute__((ext_vector_type(8)));
typedef float floatx4 __attribute__((ext_vector_type(4)));

#define NCC 65536
#define NPP 1024
#define DD 256

static __device__ __forceinline__ ushort_t f2h_bits(float x) {
  _Float16 h = (_Float16)x;
  return __builtin_bit_cast(ushort_t, h);
}
static __device__ __forceinline__ ushort_t f2bf_bits(float x) {
  unsigned u = __builtin_bit_cast(unsigned, x);
  unsigned r = (u + 0x7FFFu + ((u >> 16) & 1u)) >> 16;
  return (ushort_t)r;
}

// async global->LDS DMA, 16B per lane; LDS dest = wave-uniform base + lane*16
static __device__ __forceinline__ void dma16(const void* g, void* l) {
  __builtin_amdgcn_global_load_lds((const __attribute__((address_space(1))) unsigned int*)g,
                                   (__attribute__((address_space(3))) unsigned int*)l, 16, 0, 0);
}

// ---------------------------------------------------------------------------
// K0: transpose Wq/Wk (fp32 [k][n]) -> WT (f16 [n][k]) with XOR-8 group
// swizzle on k so contiguous DMA staging is bank-balanced for MFMA frags.
// stored half-index: k' = k XOR ((n & 7) << 3)
// ---------------------------------------------------------------------------
__global__ __launch_bounds__(256) void wt_prep(const float* __restrict__ Wq,
                                               const float* __restrict__ Wk,
                                               ushort_t* __restrict__ WqT,
                                               ushort_t* __restrict__ WkT) {
  __shared__ __align__(16) ushort_t lt[64][80];
  const float* W = blockIdx.y ? Wk : Wq;
  ushort_t* WT = blockIdx.y ? WkT : WqT;
  const int k0 = ((int)blockIdx.x & 3) * 64, n0 = ((int)blockIdx.x >> 2) * 64;
  const int t = threadIdx.x;
#pragma unroll
  for (int i = 0; i < 4; i++) {
    int f = t + 256 * i;
    int k = f >> 4, j = (f & 15) * 4;
    const float4 v = *(const float4*)&W[(size_t)(k0 + k) * DD + n0 + j];
    lt[j + 0][k] = f2h_bits(v.x);
    lt[j + 1][k] = f2h_bits(v.y);
    lt[j + 2][k] = f2h_bits(v.z);
    lt[j + 3][k] = f2h_bits(v.w);
  }
  __syncthreads();
#pragma unroll
  for (int i = 0; i < 2; i++) {
    int f = t + 256 * i;
    int nl = f >> 3, grp = f & 7;
    int n = n0 + nl;
    int kp = k0 + ((grp ^ (n & 7)) * 8);
    *(uint4*)&WT[(size_t)n * DD + kp] = *(const uint4*)&lt[nl][grp * 8];
  }
}

// ---------------------------------------------------------------------------
// K1: fused GEMM producing keyf (scaled) and query, both f16 row-major.
// Also writes xy[] = (xs, ys) float2 per candidate.
// ---------------------------------------------------------------------------
__global__ __launch_bounds__(256) void prep_gemm(
    const float* __restrict__ box_feat, const float* __restrict__ points_feat,
    const float* __restrict__ centers, const float* __restrict__ scales,
    const ushort_t* __restrict__ WqT, const ushort_t* __restrict__ WkT,
    const float* __restrict__ bq, const float* __restrict__ bk,
    ushort_t* __restrict__ q_out, ushort_t* __restrict__ kf_out,
    float2* __restrict__ xy) {
  __shared__ __align__(16) ushort_t lds_a[64][264];   // A rows (m=64, k=256), pad 8
  __shared__ __align__(16) ushort_t lds_b[64 * 256];  // W^T panel (n=64, k=256), swizzled
  __shared__ float lds_s[64];

  const int t = threadIdx.x;
  const bool isQ = (blockIdx.x >= (NCC / 64));
  const int row0 = isQ ? ((int)blockIdx.x - NCC / 64) * 64 : (int)blockIdx.x * 64;
  const float* In = isQ ? points_feat : box_feat;
  const ushort_t* WT = isQ ? WqT : WkT;
  const float* Bi = isQ ? bq : bk;
  ushort_t* Out = isQ ? q_out : kf_out;

  if (t < 64) {
    float s = 1.0f;
    if (!isQ) {
      int c = row0 + t;
      float stride = centers[c * 4 + 3];
      int lvl = (int)(log2f(stride) + 0.5f) - 3;
      lvl = lvl < 0 ? 0 : (lvl > 4 ? 4 : lvl);
      s = scales[lvl];
      float hf = floorf(centers[c * 4 + 2] * 0.5f);
      // xy = (xs, ys)
      xy[c] = make_float2(centers[c * 4 + 1] + hf, centers[c * 4 + 0] + hf);
    }
    lds_s[t] = s;
  }
  __syncthreads();

  // stage A: 64 rows x 256 cols fp32 -> scaled f16 (padded rows)
#pragma unroll
  for (int i = 0; i < 16; i++) {
    int f = t + 256 * i;
    int r = f >> 6;
    int c4 = (f & 63) * 4;
    const float4 v = *(const float4*)&In[(size_t)(row0 + r) * DD + c4];
    float s = lds_s[r];
    ushort_t h0 = f2h_bits(v.x * s), h1 = f2h_bits(v.y * s);
    ushort_t h2 = f2h_bits(v.z * s), h3 = f2h_bits(v.w * s);
    *(uint2*)&lds_a[r][c4] =
        make_uint2((unsigned)h0 | ((unsigned)h1 << 16), (unsigned)h2 | ((unsigned)h3 << 16));
  }

  const int w = t >> 6, lane = t & 63, qd = lane >> 4, n = lane & 15;
  const int sw8 = (n & 7) * 8;

  for (int g = 0; g < 4; ++g) {
    __syncthreads();  // lds_b reusable; also covers A-stage completion at g=0
    // stage W^T panel rows g*64..g*64+64 (32KB contiguous) via DMA
#pragma unroll
    for (int j = 0; j < 8; ++j) {
      int sg = w * 8 + j;
      dma16(&WT[(size_t)g * 64 * DD + sg * 512 + lane * 8], &lds_b[sg * 512 + lane * 8]);
    }
    __syncthreads();

    floatx4 acc[4] = {};
#pragma unroll
    for (int s = 0; s < 8; s++) {
      half8 af = __builtin_bit_cast(half8, *(const uint4*)&lds_a[w * 16 + n][s * 32 + qd * 8]);
      int off = (s * 32 + qd * 8) ^ sw8;
#pragma unroll
      for (int nt = 0; nt < 4; ++nt) {
        half8 bf = __builtin_bit_cast(half8, *(const uint4*)&lds_b[(nt * 16 + n) * 256 + off]);
        acc[nt] = __builtin_amdgcn_mfma_f32_16x16x32_f16(af, bf, acc[nt], 0, 0, 0);
      }
    }
    // epilogue: C/D layout row=4*qd+r, col=lane&15
#pragma unroll
    for (int nt = 0; nt < 4; ++nt) {
#pragma unroll
      for (int r = 0; r < 4; r++) {
        int row = row0 + w * 16 + qd * 4 + r;
        int col = g * 64 + nt * 16 + n;
        Out[(size_t)row * DD + col] = f2h_bits(acc[nt][r] + Bi[col]);
      }
    }
  }
}

// ---------------------------------------------------------------------------
// K2: transpose box_feat (fp32 [NC][256]) -> vT (bf16 [256][NC])
// ---------------------------------------------------------------------------
__global__ __launch_bounds__(256) void transpose_v(const float* __restrict__ box_feat,
                                                   ushort_t* __restrict__ vT) {
  __shared__ __align__(16) ushort_t lt[64][72];
  const int t = threadIdx.x;
  const int c0 = blockIdx.x * 64, d0 = blockIdx.y * 64;
#pragma unroll
  for (int i = 0; i < 4; i++) {
    int f = t + 256 * i;
    int c = f >> 4;
    int j = (f & 15) * 4;
    const float4 v = *(const float4*)&box_feat[(size_t)(c0 + c) * DD + d0 + j];
    lt[j + 0][c] = f2bf_bits(v.x);
    lt[j + 1][c] = f2bf_bits(v.y);
    lt[j + 2][c] = f2bf_bits(v.z);
    lt[j + 3][c] = f2bf_bits(v.w);
  }
  __syncthreads();
#pragma unroll
  for (int i = 0; i < 4; i++) {
    int f = t + 256 * i;
    int d = f >> 4;
    int j = (f & 15) * 4;
    *(uint2*)&vT[(size_t)(d0 + d) * NCC + c0 + j] = *(const uint2*)&lt[d][j];
  }
}

// ---------------------------------------------------------------------------
// K3: fused attention, single-barrier double-buffered pipeline.
// Block = 4 waves x 32 points; grid (64 chunks, 8 p-groups); chunk c -> XCD
// c%8 so chunk tiles stay in one L2. Per iter (32 candidates):
//   barrier (vT buf ready) -> QK via GLOBAL kf A-frag loads (vmem pipe, no
//   LDS) -> issue DMA for next vT tile into other buffer (drains at NEXT
//   barrier, hidden by PV+QK) -> mask/exp -> P through per-wave LDS -> PV
//   bf16 MFMA from lds_v. Partials -> global atomics.
// LDS reads: 18 b128/wave-iter (was 34). One __syncthreads/iter (was 2).
// ---------------------------------------------------------------------------
__global__ __launch_bounds__(256, 2) void attn_kernel(
    const ushort_t* __restrict__ qf16, const ushort_t* __restrict__ kf16,
    const ushort_t* __restrict__ vT, const float2* __restrict__ xy,
    const float* __restrict__ boxes, float* __restrict__ acc_out,
    float* __restrict__ den_out) {
  __shared__ __align__(16) ushort_t lds_v[2][256 * 32];  // vT tile dbuf [d][c]
  __shared__ __align__(16) ushort_t lds_p[4][32][40];    // per-wave P^T [p][c] bf16
  __shared__ __align__(16) float2 lds_xy[2][32];

  const int t = threadIdx.x;
  const int w = t >> 6, lane = t & 63, qd = lane >> 4, n = lane & 15;
  const int p0w = blockIdx.y * 128 + w * 32;
  const int cchunk = blockIdx.x * 1024;

  // resident query B-frags for 2 p-tiles + their boxes
  half8 qfr[2][8];
  float4 bxv[2];
#pragma unroll
  for (int pt = 0; pt < 2; ++pt) {
    int p = p0w + pt * 16 + n;
#pragma unroll
    for (int s = 0; s < 8; s++)
      qfr[pt][s] =
          __builtin_bit_cast(half8, *(const uint4*)&qf16[(size_t)p * DD + s * 32 + qd * 8]);
    bxv[pt] = *(const float4*)&boxes[p * 4];
  }

  floatx4 macc[2][16] = {};
  float dsum0 = 0.f, dsum1 = 0.f;

  // stage vT tile `it` (+xy) into buffer `buf`
  auto stage = [&](int it, int buf) {
    const int cb = cchunk + it * 32;
#pragma unroll
    for (int j = 0; j < 4; ++j) {
      int sg = w * 4 + j;
      int d = sg * 16 + (lane >> 2);
      dma16(&vT[(size_t)d * NCC + cb + (lane & 3) * 8],
            &lds_v[buf][d * 32 + (lane & 3) * 8]);
    }
    if (w == 0 && lane < 16)
      dma16(&((const float*)xy)[(size_t)cb * 2 + lane * 4], &((float*)lds_xy[buf])[lane * 4]);
  };

  stage(0, 0);

  for (int it = 0; it < 32; ++it) {
    const int buf = it & 1;
    const int cb = cchunk + it * 32;
    __syncthreads();  // lds_v[buf]/lds_xy[buf] ready; prev readers of other buf done

    // QK^T: A-frags straight from global (L1/L2-resident tile), B = qfr
#pragma unroll
    for (int t2 = 0; t2 < 2; ++t2) {
      const uint4* kr = (const uint4*)&kf16[(size_t)(cb + t2 * 16 + n) * DD + qd * 8];
      floatx4 a0 = {}, a1 = {};
#pragma unroll
      for (int s = 0; s < 8; s++) {
        half8 af = __builtin_bit_cast(half8, kr[s * 4]);
        a0 = __builtin_amdgcn_mfma_f32_16x16x32_f16(af, qfr[0][s], a0, 0, 0, 0);
        a1 = __builtin_amdgcn_mfma_f32_16x16x32_f16(af, qfr[1][s], a1, 0, 0, 0);
      }
      unsigned pk00 = 0, pk01 = 0, pk10 = 0, pk11 = 0;
#pragma unroll
      for (int r = 0; r < 4; r++) {
        int cl = t2 * 16 + qd * 4 + r;
        float2 p_xy = lds_xy[buf][cl];
        {
          float mn = fminf(fminf(p_xy.x - bxv[0].x, p_xy.y - bxv[0].y),
                           fminf(bxv[0].z - p_xy.x, bxv[0].w - p_xy.y));
          float sim = fminf(fmaxf(a0[r], -50.f), 50.f);
          float e = (mn > 0.f) ? exp2f((sim - 50.f) * 1.44269504f) : 0.f;
          dsum0 += e;
          unsigned b = (unsigned)f2bf_bits(e);
          if (r == 0) pk00 = b;
          else if (r == 1) pk00 |= b << 16;
          else if (r == 2) pk01 = b;
          else pk01 |= b << 16;
        }
        {
          float mn = fminf(fminf(p_xy.x - bxv[1].x, p_xy.y - bxv[1].y),
                           fminf(bxv[1].z - p_xy.x, bxv[1].w - p_xy.y));
          float sim = fminf(fmaxf(a1[r], -50.f), 50.f);
          float e = (mn > 0.f) ? exp2f((sim - 50.f) * 1.44269504f) : 0.f;
          dsum1 += e;
          unsigned b = (unsigned)f2bf_bits(e);
          if (r == 0) pk10 = b;
          else if (r == 1) pk10 |= b << 16;
          else if (r == 2) pk11 = b;
          else pk11 |= b << 16;
        }
      }
      *(uint2*)&lds_p[w][n][t2 * 16 + qd * 4] = make_uint2(pk00, pk01);
      *(uint2*)&lds_p[w][16 + n][t2 * 16 + qd * 4] = make_uint2(pk10, pk11);
    }

    // prefetch next vT tile into the other buffer; its latency is hidden by
    // the PV phase below + next iter's QK, drained at the next barrier.
    if (it + 1 < 32) stage(it + 1, buf ^ 1);

    // same-wave LDS RAW: drain our ds_writes before reading lds_p
    __asm__ volatile("s_waitcnt lgkmcnt(0)" ::: "memory");

    short8 a20 = __builtin_bit_cast(short8, *(const uint4*)&lds_p[w][n][qd * 8]);
    short8 a21 = __builtin_bit_cast(short8, *(const uint4*)&lds_p[w][16 + n][qd * 8]);
#pragma unroll
    for (int dt = 0; dt < 16; ++dt) {
      short8 b2 =
          __builtin_bit_cast(short8, *(const uint4*)&lds_v[buf][(dt * 16 + n) * 32 + qd * 8]);
      macc[0][dt] = __builtin_amdgcn_mfma_f32_16x16x32_bf16(a20, b2, macc[0][dt], 0, 0, 0);
      macc[1][dt] = __builtin_amdgcn_mfma_f32_16x16x32_bf16(a21, b2, macc[1][dt], 0, 0, 0);
    }
  }

  // denom: lanes l, l^16, l^32, l^48 share the same point column
  dsum0 += __shfl_xor(dsum0, 16, 64);
  dsum0 += __shfl_xor(dsum0, 32, 64);
  dsum1 += __shfl_xor(dsum1, 16, 64);
  dsum1 += __shfl_xor(dsum1, 32, 64);
  if (lane < 16) {
    atomicAdd(&den_out[p0w + n], dsum0);
    atomicAdd(&den_out[p0w + 16 + n], dsum1);
  }

  // merge partials: C/D layout row(p)=4qd+r, col(d)=dt*16+n
#pragma unroll
  for (int pt = 0; pt < 2; ++pt) {
#pragma unroll
    for (int dt = 0; dt < 16; ++dt) {
#pragma unroll
      for (int r = 0; r < 4; r++) {
        atomicAdd(&acc_out[(size_t)(p0w + pt * 16 + qd * 4 + r) * DD + dt * 16 + n],
                  macc[pt][dt][r]);
      }
    }
  }
}

// ---------------------------------------------------------------------------
// K4: out = points_feat + acc/den (guard empty columns)
// ---------------------------------------------------------------------------
__global__ void finalize(const float* __restrict__ points_feat, const float* __restrict__ acc,
                         const float* __restrict__ den, float* __restrict__ out) {
  int p = blockIdx.x, d = threadIdx.x;
  float dn = den[p];
  float m = (dn > 0.f) ? acc[p * DD + d] / dn : 0.f;
  out[p * DD + d] = points_feat[p * DD + d] + m;
}

extern "C" void kernel_launch(void* const* d_in, const int* in_sizes, int n_in, void* d_out,
                              int out_size, void* d_ws, size_t ws_size, hipStream_t stream) {
  const float* points_feat = (const float*)d_in[0];
  const float* box_feat = (const float*)d_in[1];
  const float* centers = (const float*)d_in[2];
  const float* boxes = (const float*)d_in[3];
  const float* Wq = (const float*)d_in[4];
  const float* bq = (const float*)d_in[5];
  const float* Wk = (const float*)d_in[6];
  const float* bk = (const float*)d_in[7];
  const float* scales = (const float*)d_in[8];

  // workspace layout (~69.5 MB)
  ushort_t* ws_q = (ushort_t*)d_ws;                   // 1024*256 f16
  ushort_t* ws_kf = ws_q + (size_t)NPP * DD;          // 65536*256 f16
  ushort_t* ws_vT = ws_kf + (size_t)NCC * DD;         // 256*65536 bf16
  float2* ws_xy = (float2*)(ws_vT + (size_t)NCC * DD);  // 65536 float2
  float* ws_acc = (float*)(ws_xy + NCC);              // 1024*256 f32
  float* ws_den = ws_acc + (size_t)NPP * DD;          // 1024 f32
  ushort_t* ws_wqT = (ushort_t*)(ws_den + NPP);       // 256*256 f16 (swizzled)
  ushort_t* ws_wkT = ws_wqT + DD * DD;                // 256*256 f16 (swizzled)

  hipMemsetAsync(ws_acc, 0, ((size_t)NPP * DD + NPP) * sizeof(float), stream);
  wt_prep<<<dim3(16, 2), 256, 0, stream>>>(Wq, Wk, ws_wqT, ws_wkT);
  prep_gemm<<<NCC / 64 + NPP / 64, 256, 0, stream>>>(box_feat, points_feat, centers, scales,
                                                     ws_wqT, ws_wkT, bq, bk, ws_q, ws_kf, ws_xy);
  transpose_v<<<dim3(NCC / 64, DD / 64), 256, 0, stream>>>(box_feat, ws_vT);
  attn_kernel<<<dim3(64, 8), 256, 0, stream>>>(ws_q, ws_kf, ws_vT, ws_xy, boxes, ws_acc, ws_den);
  finalize<<<NPP, DD, 0, stream>>>(points_feat, ws_acc, ws_den, (float*)d_out);
}

// Round 4
// 282.167 us; speedup vs baseline: 1.4660x; 1.4660x over previous
//
#include <hip/hip_runtime.h>

typedef unsigned short ushort_t;
typedef _Float16 half8 __attribute__((ext_vector_type(8)));
typedef short short8 __attribute__((ext_vector_type(8)));
typedef float floatx4 __attribute__((ext_vector_type(4)));

#define NCC 65536
#define NPP 1024
#define DD 256
#define NCHUNK 64
#define VROW 36                      // padded vT tile row, halves (72B: 16-phase banks)
#define VTILE_B (256 * VROW * 2)     // 18432 B per 32-candidate vT tile

static __device__ __forceinline__ ushort_t f2h_bits(float x) {
  _Float16 h = (_Float16)x;
  return __builtin_bit_cast(ushort_t, h);
}
static __device__ __forceinline__ ushort_t f2bf_bits(float x) {
  unsigned u = __builtin_bit_cast(unsigned, x);
  unsigned r = (u + 0x7FFFu + ((u >> 16) & 1u)) >> 16;
  return (ushort_t)r;
}

// async global->LDS DMA, 16B per lane (idiom verified rounds 2-3)
static __device__ __forceinline__ void dma16(const void* g, void* l) {
  __builtin_amdgcn_global_load_lds((const __attribute__((address_space(1))) unsigned int*)g,
                                   (__attribute__((address_space(3))) unsigned int*)l, 16, 0, 0);
}

static __device__ __forceinline__ short8 mk_s8(uint2 lo, uint2 hi) {
  uint4 u;
  u.x = lo.x; u.y = lo.y; u.z = hi.x; u.w = hi.y;
  return __builtin_bit_cast(short8, u);
}

// ---------------------------------------------------------------------------
// K0: transpose Wq/Wk (fp32 [k][n]) -> WT (f16 [n][k]), k' = k ^ ((n&7)<<3)
// ---------------------------------------------------------------------------
__global__ __launch_bounds__(256) void wt_prep(const float* __restrict__ Wq,
                                               const float* __restrict__ Wk,
                                               ushort_t* __restrict__ WqT,
                                               ushort_t* __restrict__ WkT) {
  __shared__ __align__(16) ushort_t lt[64][80];
  const float* W = blockIdx.y ? Wk : Wq;
  ushort_t* WT = blockIdx.y ? WkT : WqT;
  const int k0 = ((int)blockIdx.x & 3) * 64, n0 = ((int)blockIdx.x >> 2) * 64;
  const int t = threadIdx.x;
#pragma unroll
  for (int i = 0; i < 4; i++) {
    int f = t + 256 * i;
    int k = f >> 4, j = (f & 15) * 4;
    const float4 v = *(const float4*)&W[(size_t)(k0 + k) * DD + n0 + j];
    lt[j + 0][k] = f2h_bits(v.x);
    lt[j + 1][k] = f2h_bits(v.y);
    lt[j + 2][k] = f2h_bits(v.z);
    lt[j + 3][k] = f2h_bits(v.w);
  }
  __syncthreads();
#pragma unroll
  for (int i = 0; i < 2; i++) {
    int f = t + 256 * i;
    int nl = f >> 3, grp = f & 7;
    int n = n0 + nl;
    int kp = k0 + ((grp ^ (n & 7)) * 8);
    *(uint4*)&WT[(size_t)n * DD + kp] = *(const uint4*)&lt[nl][grp * 8];
  }
}

// ---------------------------------------------------------------------------
// K1: fused GEMM producing keyf (scaled, k-group swizzled) + query (plain),
// f16. Epilogue staged through lds_o -> coalesced 16B global stores.
// ---------------------------------------------------------------------------
__global__ __launch_bounds__(256) void prep_gemm(
    const float* __restrict__ box_feat, const float* __restrict__ points_feat,
    const float* __restrict__ centers, const float* __restrict__ scales,
    const ushort_t* __restrict__ WqT, const ushort_t* __restrict__ WkT,
    const float* __restrict__ bq, const float* __restrict__ bk,
    ushort_t* __restrict__ q_out, ushort_t* __restrict__ kf_out,
    float2* __restrict__ xy) {
  __shared__ __align__(16) ushort_t lds_a[64][264];
  __shared__ __align__(16) ushort_t lds_b[64 * 256];
  __shared__ __align__(16) ushort_t lds_o[64][72];
  __shared__ float lds_s[64];

  const int t = threadIdx.x;
  const bool isQ = (blockIdx.x >= (NCC / 64));
  const int row0 = isQ ? ((int)blockIdx.x - NCC / 64) * 64 : (int)blockIdx.x * 64;
  const float* In = isQ ? points_feat : box_feat;
  const ushort_t* WT = isQ ? WqT : WkT;
  const float* Bi = isQ ? bq : bk;
  ushort_t* Out = isQ ? q_out : kf_out;
  const int swz = isQ ? 0 : 7;

  if (t < 64) {
    float s = 1.0f;
    if (!isQ) {
      int c = row0 + t;
      float stride = centers[c * 4 + 3];
      int lvl = (int)(log2f(stride) + 0.5f) - 3;
      lvl = lvl < 0 ? 0 : (lvl > 4 ? 4 : lvl);
      s = scales[lvl];
      float hf = floorf(centers[c * 4 + 2] * 0.5f);
      xy[c] = make_float2(centers[c * 4 + 1] + hf, centers[c * 4 + 0] + hf);
    }
    lds_s[t] = s;
  }
  __syncthreads();

#pragma unroll
  for (int i = 0; i < 16; i++) {
    int f = t + 256 * i;
    int r = f >> 6;
    int c4 = (f & 63) * 4;
    const float4 v = *(const float4*)&In[(size_t)(row0 + r) * DD + c4];
    float s = lds_s[r];
    ushort_t h0 = f2h_bits(v.x * s), h1 = f2h_bits(v.y * s);
    ushort_t h2 = f2h_bits(v.z * s), h3 = f2h_bits(v.w * s);
    *(uint2*)&lds_a[r][c4] =
        make_uint2((unsigned)h0 | ((unsigned)h1 << 16), (unsigned)h2 | ((unsigned)h3 << 16));
  }

  const int w = t >> 6, lane = t & 63, qd = lane >> 4, n = lane & 15;
  const int sw8 = (n & 7) * 8;

  for (int g = 0; g < 4; ++g) {
    __syncthreads();  // lds_b/lds_o reusable; covers A-stage at g=0
#pragma unroll
    for (int j = 0; j < 8; ++j) {
      int sg = w * 8 + j;
      dma16(&WT[(size_t)g * 64 * DD + sg * 512 + lane * 8], &lds_b[sg * 512 + lane * 8]);
    }
    __syncthreads();

    floatx4 acc[4] = {};
#pragma unroll
    for (int s = 0; s < 8; s++) {
      half8 af = __builtin_bit_cast(half8, *(const uint4*)&lds_a[w * 16 + n][s * 32 + qd * 8]);
      int off = (s * 32 + qd * 8) ^ sw8;
#pragma unroll
      for (int nt = 0; nt < 4; ++nt) {
        half8 bf = __builtin_bit_cast(half8, *(const uint4*)&lds_b[(nt * 16 + n) * 256 + off]);
        acc[nt] = __builtin_amdgcn_mfma_f32_16x16x32_f16(af, bf, acc[nt], 0, 0, 0);
      }
    }
    // epilogue to lds_o (C/D: row=4qd+r, col=nt*16+n)
#pragma unroll
    for (int nt = 0; nt < 4; ++nt) {
      float b = Bi[g * 64 + nt * 16 + n];
#pragma unroll
      for (int r = 0; r < 4; r++) lds_o[w * 16 + qd * 4 + r][nt * 16 + n] = f2h_bits(acc[nt][r] + b);
    }
    __syncthreads();
    // coalesced copy-out with kf swizzle
#pragma unroll
    for (int i = 0; i < 2; i++) {
      int idx = t * 2 + i;
      int r = idx >> 3, grp = idx & 7;
      uint4 v = *(const uint4*)&lds_o[r][grp * 8];
      int grpS = grp ^ (swz & (r & 7));
      *(uint4*)&Out[(size_t)(row0 + r) * DD + (g * 8 + grpS) * 8] = v;
    }
  }
}

// ---------------------------------------------------------------------------
// K2: transpose box_feat (fp32 [NC][256]) -> vTb (bf16, blocked+padded:
// [tile=c/32][d=0..255][VROW], halves; last 4 halves of each row are pad)
// ---------------------------------------------------------------------------
__global__ __launch_bounds__(256) void transpose_v(const float* __restrict__ box_feat,
                                                   ushort_t* __restrict__ vTb) {
  __shared__ __align__(16) ushort_t lt[64][72];
  const int t = threadIdx.x;
  const int c0 = blockIdx.x * 64, d0 = blockIdx.y * 64;
#pragma unroll
  for (int i = 0; i < 4; i++) {
    int f = t + 256 * i;
    int c = f >> 4;
    int j = (f & 15) * 4;
    const float4 v = *(const float4*)&box_feat[(size_t)(c0 + c) * DD + d0 + j];
    lt[j + 0][c] = f2bf_bits(v.x);
    lt[j + 1][c] = f2bf_bits(v.y);
    lt[j + 2][c] = f2bf_bits(v.z);
    lt[j + 3][c] = f2bf_bits(v.w);
  }
  __syncthreads();
#pragma unroll
  for (int i = 0; i < 2; i++) {
    int f = t + 256 * i;       // 0..511 -> 64 d x 8 c-groups
    int d = f >> 3, j = f & 7;
    int tile = (c0 >> 5) + (j >> 2);
    size_t ob = (size_t)tile * (256 * VROW) + (size_t)(d0 + d) * VROW + (j & 3) * 8;
    const uint2* src = (const uint2*)&lt[d][j * 8];
    *(uint2*)&vTb[ob] = src[0];
    *(uint2*)&vTb[ob + 4] = src[1];
  }
}

// ---------------------------------------------------------------------------
// K3: fused attention. Block = 4 waves x 32 points; grid (64 chunks, 8 pg).
// Single barrier per iter; kf+vT double-buffered, staged by DMA issued right
// after the barrier (drains at the NEXT barrier -> full-iter hiding).
// PART=true: per-chunk partials via plain stores; else atomicAdd fallback.
// ---------------------------------------------------------------------------
template <bool PART>
__global__ __launch_bounds__(256, 2) void attn_kernel(
    const ushort_t* __restrict__ qf16, const ushort_t* __restrict__ kf16,
    const ushort_t* __restrict__ vTb, const float2* __restrict__ xy,
    const float* __restrict__ boxes, float* __restrict__ acc_out,
    float* __restrict__ den_out) {
  __shared__ __align__(16) ushort_t lds_k[2][32 * 256];   // kf tile (swizzled rows)
  __shared__ __align__(16) ushort_t lds_v[2][256 * VROW]; // vT tile (padded rows)
  __shared__ __align__(16) ushort_t lds_p[4][32][VROW];   // per-wave P^T bf16

  const int t = threadIdx.x;
  const int w = t >> 6, lane = t & 63, qd = lane >> 4, n = lane & 15;
  const int chunk = blockIdx.x;
  const int p0w = blockIdx.y * 128 + w * 32;
  const int cchunk = chunk * 1024;
  const int sw16 = (n & 7) * 16;  // byte XOR for kf frag reads

  half8 qfr[2][8];
  float4 bxv[2];
#pragma unroll
  for (int pt = 0; pt < 2; ++pt) {
    int p = p0w + pt * 16 + n;
#pragma unroll
    for (int s = 0; s < 8; s++)
      qfr[pt][s] =
          __builtin_bit_cast(half8, *(const uint4*)&qf16[(size_t)p * DD + s * 32 + qd * 8]);
    bxv[pt] = *(const float4*)&boxes[p * 4];
  }

  floatx4 macc[2][16] = {};
  float dsum0 = 0.f, dsum1 = 0.f;

  auto stage = [&](int it, int buf) {
    const size_t kbase = (size_t)(cchunk + it * 32) * DD * 2;  // bytes
#pragma unroll
    for (int j = 0; j < 4; ++j) {
      int i = w * 4 + j;
      dma16((const char*)kf16 + kbase + i * 1024 + lane * 16,
            (char*)lds_k[buf] + i * 1024 + lane * 16);
    }
    const size_t vbase = (size_t)((cchunk >> 5) + it) * VTILE_B;
#pragma unroll
    for (int j = 0; j < 4; ++j) {
      int i = j * 4 + w;
      dma16((const char*)vTb + vbase + i * 1024 + lane * 16,
            (char*)lds_v[buf] + i * 1024 + lane * 16);
    }
    if (w < 2) {
      int i = 16 + w;
      dma16((const char*)vTb + vbase + i * 1024 + lane * 16,
            (char*)lds_v[buf] + i * 1024 + lane * 16);
    }
  };

  stage(0, 0);

  for (int it = 0; it < 32; ++it) {
    const int buf = it & 1;
    const int cb = cchunk + it * 32;
    __syncthreads();  // drains stage(it); prev iter's reads of buf^1 done
    if (it + 1 < 32) stage(it + 1, buf ^ 1);  // drains at NEXT barrier

    // QK^T from lds_k[buf] (XOR-swizzled rows, bank-balanced)
#pragma unroll
    for (int t2 = 0; t2 < 2; ++t2) {
      const char* krow = (const char*)lds_k[buf] + (t2 * 16 + n) * 512;
      floatx4 a0 = {}, a1 = {};
#pragma unroll
      for (int s = 0; s < 8; s++) {
        half8 af = __builtin_bit_cast(half8, *(const uint4*)(krow + ((s * 64 + qd * 16) ^ sw16)));
        a0 = __builtin_amdgcn_mfma_f32_16x16x32_f16(af, qfr[0][s], a0, 0, 0, 0);
        a1 = __builtin_amdgcn_mfma_f32_16x16x32_f16(af, qfr[1][s], a1, 0, 0, 0);
      }
      unsigned pk00 = 0, pk01 = 0, pk10 = 0, pk11 = 0;
#pragma unroll
      for (int r = 0; r < 4; r++) {
        int cl = t2 * 16 + qd * 4 + r;
        float2 pxy = xy[cb + cl];  // L1/L2-resident, wave-uniform per 16 lanes
        {
          float mn = fminf(fminf(pxy.x - bxv[0].x, pxy.y - bxv[0].y),
                           fminf(bxv[0].z - pxy.x, bxv[0].w - pxy.y));
          float sim = fminf(fmaxf(a0[r], -50.f), 50.f);
          float e = (mn > 0.f) ? exp2f((sim - 50.f) * 1.44269504f) : 0.f;
          dsum0 += e;
          unsigned b = (unsigned)f2bf_bits(e);
          if (r == 0) pk00 = b;
          else if (r == 1) pk00 |= b << 16;
          else if (r == 2) pk01 = b;
          else pk01 |= b << 16;
        }
        {
          float mn = fminf(fminf(pxy.x - bxv[1].x, pxy.y - bxv[1].y),
                           fminf(bxv[1].z - pxy.x, bxv[1].w - pxy.y));
          float sim = fminf(fmaxf(a1[r], -50.f), 50.f);
          float e = (mn > 0.f) ? exp2f((sim - 50.f) * 1.44269504f) : 0.f;
          dsum1 += e;
          unsigned b = (unsigned)f2bf_bits(e);
          if (r == 0) pk10 = b;
          else if (r == 1) pk10 |= b << 16;
          else if (r == 2) pk11 = b;
          else pk11 |= b << 16;
        }
      }
      *(uint2*)&lds_p[w][n][t2 * 16 + qd * 4] = make_uint2(pk00, pk01);
      *(uint2*)&lds_p[w][16 + n][t2 * 16 + qd * 4] = make_uint2(pk10, pk11);
    }
    // same-wave LDS RAW on lds_p (DS ops only; DMA uses vmcnt)
    __asm__ volatile("s_waitcnt lgkmcnt(0)" ::: "memory");

    const char* pr0 = (const char*)&lds_p[w][n][0];
    const char* pr1 = (const char*)&lds_p[w][16 + n][0];
    short8 a20 = mk_s8(*(const uint2*)(pr0 + qd * 16), *(const uint2*)(pr0 + qd * 16 + 8));
    short8 a21 = mk_s8(*(const uint2*)(pr1 + qd * 16), *(const uint2*)(pr1 + qd * 16 + 8));
#pragma unroll
    for (int dt = 0; dt < 16; ++dt) {
      const char* vrow = (const char*)lds_v[buf] + (dt * 16 + n) * (VROW * 2);
      short8 b2 = mk_s8(*(const uint2*)(vrow + qd * 16), *(const uint2*)(vrow + qd * 16 + 8));
      macc[0][dt] = __builtin_amdgcn_mfma_f32_16x16x32_bf16(a20, b2, macc[0][dt], 0, 0, 0);
      macc[1][dt] = __builtin_amdgcn_mfma_f32_16x16x32_bf16(a21, b2, macc[1][dt], 0, 0, 0);
    }
  }

  dsum0 += __shfl_xor(dsum0, 16, 64);
  dsum0 += __shfl_xor(dsum0, 32, 64);
  dsum1 += __shfl_xor(dsum1, 16, 64);
  dsum1 += __shfl_xor(dsum1, 32, 64);

  if (PART) {
    if (lane < 16) {
      den_out[(size_t)chunk * NPP + p0w + n] = dsum0;
      den_out[(size_t)chunk * NPP + p0w + 16 + n] = dsum1;
    }
    float* ab = acc_out + (size_t)chunk * NPP * DD;
#pragma unroll
    for (int pt = 0; pt < 2; ++pt)
#pragma unroll
      for (int dt = 0; dt < 16; ++dt)
#pragma unroll
        for (int r = 0; r < 4; r++)
          ab[(size_t)(p0w + pt * 16 + qd * 4 + r) * DD + dt * 16 + n] = macc[pt][dt][r];
  } else {
    if (lane < 16) {
      atomicAdd(&den_out[p0w + n], dsum0);
      atomicAdd(&den_out[p0w + 16 + n], dsum1);
    }
#pragma unroll
    for (int pt = 0; pt < 2; ++pt)
#pragma unroll
      for (int dt = 0; dt < 16; ++dt)
#pragma unroll
        for (int r = 0; r < 4; r++)
          atomicAdd(&acc_out[(size_t)(p0w + pt * 16 + qd * 4 + r) * DD + dt * 16 + n],
                    macc[pt][dt][r]);
  }
}

// ---------------------------------------------------------------------------
// K4a: reduce partials over chunks + finalize (PART path)
// ---------------------------------------------------------------------------
__global__ __launch_bounds__(256) void reduce_finalize(const float* __restrict__ points_feat,
                                                       const float* __restrict__ acc_part,
                                                       const float* __restrict__ den_part,
                                                       float* __restrict__ out) {
  const int p = blockIdx.x, t = threadIdx.x;
  float s = 0.f;
#pragma unroll 4
  for (int c = 0; c < NCHUNK; ++c) s += acc_part[((size_t)c * NPP + p) * DD + t];
  float dn = den_part[(size_t)(t & 63) * NPP + p];
#pragma unroll
  for (int o = 1; o < 64; o <<= 1) dn += __shfl_xor(dn, o, 64);
  float m = (dn > 0.f) ? s / dn : 0.f;
  out[(size_t)p * DD + t] = points_feat[(size_t)p * DD + t] + m;
}

// K4b: atomic-path finalize
__global__ void finalize(const float* __restrict__ points_feat, const float* __restrict__ acc,
                         const float* __restrict__ den, float* __restrict__ out) {
  int p = blockIdx.x, d = threadIdx.x;
  float dn = den[p];
  float m = (dn > 0.f) ? acc[p * DD + d] / dn : 0.f;
  out[p * DD + d] = points_feat[p * DD + d] + m;
}

extern "C" void kernel_launch(void* const* d_in, const int* in_sizes, int n_in, void* d_out,
                              int out_size, void* d_ws, size_t ws_size, hipStream_t stream) {
  const float* points_feat = (const float*)d_in[0];
  const float* box_feat = (const float*)d_in[1];
  const float* centers = (const float*)d_in[2];
  const float* boxes = (const float*)d_in[3];
  const float* Wq = (const float*)d_in[4];
  const float* bq = (const float*)d_in[5];
  const float* Wk = (const float*)d_in[6];
  const float* bk = (const float*)d_in[7];
  const float* scales = (const float*)d_in[8];

  char* p = (char*)d_ws;
  ushort_t* ws_q = (ushort_t*)p;        p += (size_t)NPP * DD * 2;
  ushort_t* ws_kf = (ushort_t*)p;       p += (size_t)NCC * DD * 2;
  ushort_t* ws_vTb = (ushort_t*)p;      p += (size_t)(NCC / 32) * VTILE_B;
  float2* ws_xy = (float2*)p;           p += (size_t)NCC * 8;
  ushort_t* ws_wqT = (ushort_t*)p;      p += (size_t)DD * DD * 2;
  ushort_t* ws_wkT = (ushort_t*)p;      p += (size_t)DD * DD * 2;
  float* ws_den = (float*)p;            p += (size_t)NCHUNK * NPP * 4;
  float* ws_acc = (float*)p;
  size_t need_part = (size_t)(p - (char*)d_ws) + (size_t)NCHUNK * NPP * DD * 4;
  const bool part = ws_size >= need_part;

  wt_prep<<<dim3(16, 2), 256, 0, stream>>>(Wq, Wk, ws_wqT, ws_wkT);
  prep_gemm<<<NCC / 64 + NPP / 64, 256, 0, stream>>>(box_feat, points_feat, centers, scales,
                                                     ws_wqT, ws_wkT, bq, bk, ws_q, ws_kf, ws_xy);
  transpose_v<<<dim3(NCC / 64, DD / 64), 256, 0, stream>>>(box_feat, ws_vTb);
  if (part) {
    attn_kernel<true><<<dim3(NCHUNK, 8), 256, 0, stream>>>(ws_q, ws_kf, ws_vTb, ws_xy, boxes,
                                                           ws_acc, ws_den);
    reduce_finalize<<<NPP, 256, 0, stream>>>(points_feat, ws_acc, ws_den, (float*)d_out);
  } else {
    hipMemsetAsync(ws_den, 0, ((size_t)NPP * DD + NPP) * sizeof(float), stream);
    float* acc1 = ws_den + NPP;  // reuse region: den (1024) + acc (1024*256)
    attn_kernel<false><<<dim3(NCHUNK, 8), 256, 0, stream>>>(ws_q, ws_kf, ws_vTb, ws_xy, boxes,
                                                            acc1, ws_den);
    finalize<<<NPP, DD, 0, stream>>>(points_feat, acc1, ws_den, (float*)d_out);
  }
}